// Round 2
// baseline (1219.771 us; speedup 1.0000x reference)
//
#include <hip/hip_runtime.h>

// IDWT_2D Haar: B=4, Ct=256 (C=64 groups x 4 subbands), H=W=256 -> out [4,256,512,512]
// y[b, g*4+j, 2h+a, 2w+c] = (sum_n x[b, n*64+g, h, w]) * filters[j,a,c]
//
// HBM-bound: 256 MiB in + 1 GiB out => ~215 us kernel floor at 6.3 TB/s.
// (Harness dur_us also includes a ~690 us 4-GiB poison fill.)
//
// v2 theory: previous versions had per-instruction-contiguous but AGGREGATE-
// fragmented writes (each thread scatters 8 chunks across 4 channels x 2 rows;
// ~100K concurrent 1-KiB islands at the memory controller). This version gives
// each WAVE a fully sequential 64-KiB store stream: block=(b,g,16 h-rows),
// phase 1 cooperatively reduces the 4 subbands into LDS s[16][256], phase 2
// wave j sweeps output channel g*4+j rows 2h0..2h0+31 in address order.

#define B   4
#define C   64      // wavelet groups
#define H   256
#define W   256
#define R   16      // h-rows per block
#define OW  (2 * W) // 512 output cols
#define OH  (2 * H)

typedef float f2 __attribute__((ext_vector_type(2)));
typedef float f4 __attribute__((ext_vector_type(4)));

__global__ __launch_bounds__(256) void idwt2d_haar_kernel(
    const float* __restrict__ x,     // [B, 4*C, H, W]
    const float* __restrict__ filt,  // [4, 2, 2]
    float* __restrict__ y)           // [B, 4*C, 2H, 2W]
{
    __shared__ float s_lds[R][W];    // 16 KiB

    const int t   = threadIdx.x;
    const int bid = blockIdx.x;              // ((b*C + g)*(H/R) + hb)
    const int hb  = bid & (H / R - 1);       // 4 bits
    const int g   = (bid >> 4) & (C - 1);    // 6 bits
    const int b   = bid >> 10;
    const int h0  = hb * R;

    // ---- phase 1: s[r][:] = sum_n x[b, n*C+g, h0+r, :] ----
    const int w4 = t & 63;   // f4 chunk within row (lane id)
    const int rq = t >> 6;   // 0..3 (wave id)
    const int nstride = C * H * W;

#pragma unroll
    for (int rr = 0; rr < 4; ++rr) {
        const int r = rq + 4 * rr;
        const int base = (((b * (4 * C)) + g) * H + (h0 + r)) * W + 4 * w4;
        const f4 x0 = __builtin_nontemporal_load((const f4*)(x + base));
        const f4 x1 = __builtin_nontemporal_load((const f4*)(x + base + nstride));
        const f4 x2 = __builtin_nontemporal_load((const f4*)(x + base + 2 * nstride));
        const f4 x3 = __builtin_nontemporal_load((const f4*)(x + base + 3 * nstride));
        f4 s;
        s.x = (x0.x + x1.x) + (x2.x + x3.x);   // same reduction tree as verified kernel
        s.y = (x0.y + x1.y) + (x2.y + x3.y);
        s.z = (x0.z + x1.z) + (x2.z + x3.z);
        s.w = (x0.w + x1.w) + (x2.w + x3.w);
        *(f4*)&s_lds[r][4 * w4] = s;
    }
    __syncthreads();

    // ---- phase 2: wave j writes channel g*4+j, rows 2h0 .. 2h0+2R-1, in order ----
    const int j = t >> 6;    // wave id = subband j
    const int L = t & 63;    // lane

    const float fj00 = filt[j * 4 + 0];
    const float fj01 = filt[j * 4 + 1];
    const float fj10 = filt[j * 4 + 2];
    const float fj11 = filt[j * 4 + 3];

    float* p = y + (((b * (4 * C)) + (g * 4 + j)) * OH + 2 * h0) * OW;

#pragma unroll
    for (int r = 0; r < R; ++r) {
        const f2 sa = *(const f2*)&s_lds[r][2 * L];        // s[2L], s[2L+1]
        const f2 sb = *(const f2*)&s_lds[r][128 + 2 * L];  // s[128+2L], s[128+2L+1]
#pragma unroll
        for (int a = 0; a < 2; ++a) {
            const float f0 = a ? fj10 : fj00;
            const float f1 = a ? fj11 : fj01;
            f4 oA, oB;
            oA.x = sa.x * f0; oA.y = sa.x * f1;
            oA.z = sa.y * f0; oA.w = sa.y * f1;
            oB.x = sb.x * f0; oB.y = sb.x * f1;
            oB.z = sb.y * f0; oB.w = sb.y * f1;
            __builtin_nontemporal_store(oA, (f4*)(p + 4 * L));        // cols 0..255
            __builtin_nontemporal_store(oB, (f4*)(p + 256 + 4 * L));  // cols 256..511
            p += OW;  // next output row (addresses strictly increasing)
        }
    }
}

extern "C" void kernel_launch(void* const* d_in, const int* in_sizes, int n_in,
                              void* d_out, int out_size, void* d_ws, size_t ws_size,
                              hipStream_t stream) {
    const float* x    = (const float*)d_in[0];  // [4, 256, 256, 256] fp32
    const float* filt = (const float*)d_in[1];  // [4, 2, 2] fp32
    float* y = (float*)d_out;                   // [4, 256, 512, 512] fp32

    const int grid = B * C * (H / R);           // 4096 blocks
    idwt2d_haar_kernel<<<grid, 256, 0, stream>>>(x, filt, y);
}